// Round 2
// baseline (2183.729 us; speedup 1.0000x reference)
//
#include <hip/hip_runtime.h>

typedef unsigned short u16;
typedef __attribute__((ext_vector_type(8))) __bf16 bf16x8;
typedef __attribute__((ext_vector_type(4))) float f32x4;

#define DT_STEP 0.01f

// ---- workspace layout (bytes) ----
// All matrix operands live in "MFMA-staged layout": element (row, kk) of a
// [rows x K] K-major matrix is stored in 1KB blocks of 16 rows x 32 kk:
//   off_u16 = ((row>>4)*KB + (kk>>5))*512 + (((kk>>3)&3)*16 + (row&15))*8 + (kk&7)
// so a wave's MFMA fragment load is exactly 16B per lane at base + lane*16B
// (perfectly coalesced global_load_dwordx4, no LDS round-trip, no barriers).
//
// Wall : 3968 rows x 512 K (KB=16)  : row k*496+i = sqrt(r_k)*L_k[i,:]
// Aop2 : 496 rows x 5632 K (KB=176) : KB 0..127 = SwC (setup) then Tflat (steps)
//                                     KB 128..143 = -0.5*G
//                                     KB 144..159 = -0.5*rho slot0
//                                     KB 160..175 = -0.5*rho slot1
// Bop2 : 496 rows x 5632 K (KB=176) : KB 0..127 = SwT (sqrt(r_k)*L_k blocks)
//                                     KB 128..143 = G
//                                     KB 144..159 = rho slot0
//                                     KB 160..175 = rho slot1
// accum: 496*496 f32 split-K accumulator (re-zeroed by finalizer)
// cnt  : 64 int per-C-tile arrival counters
static const size_t OFF_WALL = 0;
static const size_t OFF_AOP2 = 4063232;    // 248*16*512*2
static const size_t OFF_BOP2 = 9650176;    // + 31*176*512*2
static const size_t OFF_ACC  = 15237120;   // + 31*176*512*2
static const size_t OFF_CNT  = 16221184;   // + 496*496*4
static const size_t WS_NEED  = 16221440;   // == previous proven footprint

static __device__ __forceinline__ u16 f2bf(float x){
  unsigned u = __float_as_uint(x);
  u = u + 0x7FFFu + ((u >> 16) & 1u);   // RNE
  return (u16)(u >> 16);
}

static __device__ __forceinline__ size_t stx(int row, int kk, int KB){
  return ((size_t)((row >> 4) * KB + (kk >> 5)) << 9)
       + (size_t)(((((kk >> 3) & 3) * 16) + (row & 15)) << 3) + (kk & 7);
}

// K0a: fill Wall (staged) and SwT region of Bop2 (staged). K-pads -> 0.
__global__ __launch_bounds__(256) void k0a(const float* __restrict__ L,
                                           const float* __restrict__ rates,
                                           u16* __restrict__ Wall,
                                           u16* __restrict__ Bop2){
  int id = blockIdx.x * 256 + threadIdx.x;
  if (id >= 8*496*512) return;
  int k   = id / (496*512);
  int rem = id - k*(496*512);
  int i   = rem >> 9;
  int j   = rem & 511;
  float rt = sqrtf(fabsf(rates[k]));
  float v = 0.0f;
  if (j < 496) v = rt * L[(size_t)k*246016 + i*496 + j];
  u16 h = f2bf(v);
  Wall[stx(k*496 + i, j, 16)] = h;
  Bop2[stx(i, (k << 9) + j, 176)] = h;
}

// K0b: SwC[i, k*512+j] = sqrt(r_k)*L_k[j,i] into Aop2 KB 0..127 (LDS transpose).
__global__ __launch_bounds__(256) void k0b(const float* __restrict__ L,
                                           const float* __restrict__ rates,
                                           u16* __restrict__ Aop2){
  __shared__ float tile[32][33];
  int k  = blockIdx.z;
  int i0 = blockIdx.x * 32;
  int j0 = blockIdx.y * 32;
  int tx = threadIdx.x, ty = threadIdx.y;  // 32 x 8
  float rt = sqrtf(fabsf(rates[k]));
  #pragma unroll
  for (int p = 0; p < 4; ++p){
    int j = j0 + ty + p*8;   // row of L_k
    int i = i0 + tx;         // col of L_k
    float v = 0.0f;
    if (j < 496 && i < 496) v = rt * L[(size_t)k*246016 + j*496 + i];
    tile[ty + p*8][tx] = v;
  }
  __syncthreads();
  #pragma unroll
  for (int p = 0; p < 4; ++p){
    int i = i0 + ty + p*8;   // SwC row
    int j = j0 + tx;         // col within k-block (pads get 0 via load guard)
    if (i < 496) Aop2[stx(i, (k << 9) + j, 176)] = f2bf(tile[tx][ty + p*8]);
  }
}

// K0c: rho into slot0 (staged), zero slot1 + G pads, d_out=rho0, accum/cnt zero.
__global__ __launch_bounds__(256) void k0c(const float* __restrict__ rho0,
                                           u16* __restrict__ Aop2,
                                           u16* __restrict__ Bop2,
                                           float* __restrict__ dout,
                                           float* __restrict__ accum,
                                           int* __restrict__ cnt){
  int id = blockIdx.x * 256 + threadIdx.x;
  if (id >= 496*512) return;
  int i = id >> 9, j = id & 511;
  float f = (j < 496) ? rho0[(size_t)i*496 + j] : 0.0f;
  Bop2[stx(i, 4608 + j, 176)] = f2bf(f);
  Aop2[stx(i, 4608 + j, 176)] = f2bf(-0.5f*f);
  Bop2[stx(i, 5120 + j, 176)] = 0;
  Aop2[stx(i, 5120 + j, 176)] = 0;
  if (j >= 496){ Bop2[stx(i, 4096 + j, 176)] = 0; Aop2[stx(i, 4096 + j, 176)] = 0; }
  if (j < 496){ dout[(size_t)i*496 + j] = f; accum[(size_t)i*496 + j] = 0.0f; }
  if (id < 64) cnt[id] = 0;
}

// Direct-to-register NT GEMM on staged operands. 64x64 C-tile, 4 waves of
// 2x2 16x16x32 bf16 MFMA, K-loop = 4 coalesced b128 loads + 4 MFMA, no LDS,
// no barriers (compiler software-pipelines across the unrolled loop).
// MODE 0: phase A, T_k = L~_k * rho (A=Wall KB16, B=rho slot). Epilogue ->
//         staged Tflat region of Aop2.
// MODE 1: G = SwC * SwC^T. Epilogue -> -0.5G (Aop2), G (Bop2), staged.
// MODE 2: phase B, K=5120 logical (Tflat*SwT + (-0.5G)*rho + (-0.5rho)*G),
//         split-K=8 over blockIdx.z, atomic accumulate; last arrival finalizes.
template<int MODE>
__global__ __launch_bounds__(256) void gemm_nt(
    const u16* __restrict__ Ast, const u16* __restrict__ Bst,
    int rhoKB, u16* __restrict__ Aop2, u16* __restrict__ Bop2,
    float* __restrict__ accum, int* __restrict__ cnt,
    float* __restrict__ dout, int rhoKBN)
{
  __shared__ int sticket;
  const int t    = threadIdx.x;
  const int lane = t & 63;
  const int w    = t >> 6;
  const int wm   = w & 1, wn = w >> 1;
  const int tm   = blockIdx.x, tn = blockIdx.y;

  int kt0 = 0, nkt;
  if (MODE == 0)      nkt = 16;
  else if (MODE == 1) nkt = 128;
  else { kt0 = blockIdx.z * 20; nkt = 20; }

  const int KBa = (MODE == 0) ? 16 : 176;
  const int KBb = 176;
  const int RA0 = tm*4 + wm*2;
  const int RB0 = tn*4 + wn*2;
  const size_t laneu = (size_t)lane * 8;
  const size_t strA = (size_t)KBa << 9;
  const size_t strB = (size_t)KBb << 9;

  f32x4 acc[2][2];
  #pragma unroll
  for (int a = 0; a < 2; ++a)
    #pragma unroll
    for (int b = 0; b < 2; ++b)
      acc[a][b] = (f32x4){0.f, 0.f, 0.f, 0.f};

  #pragma unroll 4
  for (int it = 0; it < nkt; ++it){
    int kt = kt0 + it;
    int k32a, k32b;
    if (MODE == 0){ k32a = kt; k32b = rhoKB + kt; }
    else if (MODE == 1){ k32a = kt; k32b = kt; }
    else {
      if (kt < 128)      { k32a = kt;                k32b = kt; }
      else if (kt < 144) { k32a = kt;                k32b = rhoKB + kt - 128; }
      else               { k32a = rhoKB + kt - 144;  k32b = kt - 16; }
    }
    const u16* pa = Ast + (((size_t)(RA0*KBa + k32a)) << 9) + laneu;
    const u16* pb = Bst + (((size_t)(RB0*KBb + k32b)) << 9) + laneu;
    bf16x8 a0 = *(const bf16x8*)(pa);
    bf16x8 a1 = *(const bf16x8*)(pa + strA);
    bf16x8 b0 = *(const bf16x8*)(pb);
    bf16x8 b1 = *(const bf16x8*)(pb + strB);
    acc[0][0] = __builtin_amdgcn_mfma_f32_16x16x32_bf16(a0, b0, acc[0][0], 0, 0, 0);
    acc[0][1] = __builtin_amdgcn_mfma_f32_16x16x32_bf16(a0, b1, acc[0][1], 0, 0, 0);
    acc[1][0] = __builtin_amdgcn_mfma_f32_16x16x32_bf16(a1, b0, acc[1][0], 0, 0, 0);
    acc[1][1] = __builtin_amdgcn_mfma_f32_16x16x32_bf16(a1, b1, acc[1][1], 0, 0, 0);
  }

  const int quad = lane >> 4, c16 = lane & 15;
  #pragma unroll
  for (int mi = 0; mi < 2; ++mi)
  #pragma unroll
  for (int ni = 0; ni < 2; ++ni)
  #pragma unroll
  for (int r = 0; r < 4; ++r){
    int row = tm*64 + wm*32 + mi*16 + quad*4 + r;
    int col = tn*64 + wn*32 + ni*16 + c16;
    float v = acc[mi][ni][r];
    if (MODE == 0){
      int k  = row / 496;
      int i2 = row - k*496;
      Aop2[stx(i2, (k << 9) + col, 176)] = f2bf(v);   // pads benign (SwT pads are 0)
    } else if (MODE == 1){
      if (row < 496 && col < 496){
        Bop2[stx(row, 4096 + col, 176)] = f2bf(v);
        Aop2[stx(row, 4096 + col, 176)] = f2bf(-0.5f*v);
      }
    } else {
      if (row < 496 && col < 496)
        atomicAdd(&accum[row*496 + col], v);
    }
  }

  if (MODE == 2){
    __threadfence();                               // release our partial adds
    if (t == 0) sticket = atomicAdd(&cnt[tm*8 + tn], 1);
    __syncthreads();
    if (sticket == 7){                             // last of 8 split-K blocks
      __threadfence();                             // acquire
      #pragma unroll
      for (int mi = 0; mi < 2; ++mi)
      #pragma unroll
      for (int ni = 0; ni < 2; ++ni)
      #pragma unroll
      for (int r = 0; r < 4; ++r){
        int row = tm*64 + wm*32 + mi*16 + quad*4 + r;
        int col = tn*64 + wn*32 + ni*16 + c16;
        if (row < 496 && col < 496){
          int e = row*496 + col;
          float tot = __hip_atomic_load(&accum[e], __ATOMIC_RELAXED, __HIP_MEMORY_SCOPE_AGENT);
          float rnew = dout[e] + DT_STEP * tot;
          dout[e] = rnew;                          // fp32 state lives in d_out
          Bop2[stx(row, (rhoKBN << 5) + col, 176)] = f2bf(rnew);
          Aop2[stx(row, (rhoKBN << 5) + col, 176)] = f2bf(-0.5f*rnew);
          accum[e] = 0.0f;                         // ready for next step
        }
      }
      if (t == 0) cnt[tm*8 + tn] = 0;
    }
  }
}

extern "C" void kernel_launch(void* const* d_in, const int* in_sizes, int n_in,
                              void* d_out, int out_size, void* d_ws, size_t ws_size,
                              hipStream_t stream)
{
  (void)in_sizes; (void)n_in; (void)out_size;
  if (ws_size < WS_NEED) return;
  const float* rho0  = (const float*)d_in[0];
  // d_in[1] (H_real) provably does not affect the real forward output.
  const float* L     = (const float*)d_in[2];
  const float* rates = (const float*)d_in[3];
  float* dout = (float*)d_out;
  char* ws = (char*)d_ws;
  u16* Wall    = (u16*)(ws + OFF_WALL);
  u16* Aop2    = (u16*)(ws + OFF_AOP2);
  u16* Bop2    = (u16*)(ws + OFF_BOP2);
  float* accum = (float*)(ws + OFF_ACC);
  int* cnt     = (int*)(ws + OFF_CNT);

  k0a<<<dim3((8*496*512 + 255)/256), dim3(256), 0, stream>>>(L, rates, Wall, Bop2);
  k0b<<<dim3(16,16,8), dim3(32,8), 0, stream>>>(L, rates, Aop2);
  k0c<<<dim3((496*512 + 255)/256), dim3(256), 0, stream>>>(rho0, Aop2, Bop2, dout, accum, cnt);
  // G = sum_k r_k L_k^T L_k  (once)
  gemm_nt<1><<<dim3(8,8), dim3(256), 0, stream>>>(
      Aop2, Aop2, 0, Aop2, Bop2, accum, cnt, dout, 0);

  for (int s = 0; s < 32; ++s){
    int rhoKB  = 144 + 16*(s & 1);
    int rhoKBN = 144 + 16*((s+1) & 1);
    // phase A: T_k = sqrt(r_k) L_k * rho  (rho symmetric -> row-major rho is B^T)
    gemm_nt<0><<<dim3(62,8), dim3(256), 0, stream>>>(
        Wall, Bop2, rhoKB, Aop2, Bop2, accum, cnt, dout, 0);
    // phase B: rho += DT*( sum_k T_k L~_k^T - 0.5(G rho + rho G) )
    gemm_nt<2><<<dim3(8,8,8), dim3(256), 0, stream>>>(
        Aop2, Bop2, rhoKB, Aop2, Bop2, accum, cnt, dout, rhoKBN);
  }
}